// Round 3
// baseline (114.587 us; speedup 1.0000x reference)
//
#include <hip/hip_runtime.h>
#include <hip/hip_bf16.h>
#include <math.h>

#define B_N 8192
#define E_N 512
#define T_N 32
#define BP 520  // B LDS pitch in shorts (1040 B, 16B-aligned rows)

typedef short bf16x8 __attribute__((ext_vector_type(8)));
typedef float f32x4 __attribute__((ext_vector_type(4)));

// ---------------- ws layout (bytes) ----------------
#define WS_OFFS   256      // fallback
#define WS_RANK   512      // fallback
#define WS_ORDER  33280    // fallback
#define WS_YACC   66048    // fallback
#define WS_YACC8  98816    // main: 8 x 8192 floats (256 KB), slab = nt
#define WS_REQ    (WS_YACC8 + 8 * B_N * 4)

static __device__ __forceinline__ unsigned short f2bf(float f) {
    unsigned int u = __float_as_uint(f);
    unsigned int r = u + 0x7fffu + ((u >> 16) & 1u);  // RNE
    return (unsigned short)(r >> 16);
}

// packed f32x2 -> bf16x2 (RNE)
static __device__ __forceinline__ unsigned int pk2(float a, float b) {
    __hip_bfloat162 h = __float22bfloat162_rn(float2{a, b});
    unsigned int u;
    __builtin_memcpy(&u, &h, 4);
    return u;
}

// ---------- fused GEMM v10: (tissue, 64-col slice, row-half) blocks.
// B bf16 LDS-resident (XOR-swizzled: B-prologue scalar writes were an
// 8-way bank conflict = the constant 2.9M SQ_LDS_BANK_CONFLICT; swizzle
// makes writes 2-way (free) and keeps ds_read_b128 reads balanced).
// A loaded f32 global->VGPR in-loop (k_cvtA eliminated; v8's spill was
// from full unroll, not f32 width: #pragma unroll 1 + depth-2 rolling
// prefetch bounds liveness). No main-loop barriers; 2 blocks/CU.
// wi%8 == t%8: all 16 blocks of a tissue on one XCD (L2 reuse of A rows
// and of the W1 slice shared by the two row-halves).
__global__ __launch_bounds__(512, 4) void k_gemm_mfma(
    const float* __restrict__ g_exp, const float* __restrict__ W1,
    const int* __restrict__ tv, const float* __restrict__ b1,
    const float* __restrict__ W2, float* __restrict__ yacc8) {
    int wi = blockIdx.x;
    int t = wi & 31, nt = (wi >> 5) & 7, h = wi >> 8;
    int n0 = nt * 64;

    int tid = threadIdx.x;
    int w = tid >> 6, lane = tid & 63;
    int quad = (lane >> 4) & 3, l15 = lane & 15;

    __shared__ __align__(16) unsigned short Bs[64 * BP];  // 66560 B, resident all kernel
    __shared__ int rows_s[256];  // this block's interleaved 128-row chunks
    __shared__ int wsum[8];

    // per-lane epilogue constants (cols n0 + ni*16 + l15)
    float b1v[4], w2v[4];
#pragma unroll
    for (int ni = 0; ni < 4; ++ni) {
        int n = t * E_N + n0 + ni * 16 + l15;
        b1v[ni] = b1[n];
        w2v[ni] = W2[n];
    }

    // ---- counting-sort slice for tissue t (512 thr x 16 items) ----
    int tvals[16];
    const int4* tvp = (const int4*)(tv + tid * 16);
#pragma unroll
    for (int j = 0; j < 4; ++j) ((int4*)tvals)[j] = tvp[j];
    int myc = 0;
#pragma unroll
    for (int j = 0; j < 16; ++j) myc += (tvals[j] == t) ? 1 : 0;
    int inc = myc;
#pragma unroll
    for (int o = 1; o < 64; o <<= 1) {
        int u = __shfl_up(inc, o, 64);
        if (lane >= o) inc += u;
    }
    if (lane == 63) wsum[w] = inc;
    if (tid < 256) rows_s[tid] = 0;
    __syncthreads();
    int n_t = 0, wbase = 0;
#pragma unroll
    for (int i = 0; i < 8; ++i) {
        int v = wsum[i];
        n_t += v;
        if (i < w) wbase += v;
    }
    int nt_c = n_t > 512 ? 512 : n_t;
    int rk = wbase + inc - myc;
    // scatter: half h owns 128-row chunks with (chunk & 1) == h
#pragma unroll
    for (int j = 0; j < 16; ++j)
        if (tvals[j] == t) {
            int rr = rk++;
            if (rr < 512 && (((rr >> 7) & 1) == h))
                rows_s[((rr >> 8) << 7) | (rr & 127)] = tid * 16 + j;
        }

    // ---- B prologue: W1[t][k][n0:n0+64] fp32 -> Bs[n][k] bf16 (k-major,
    // packed pairs, word idx XOR-swizzled by ((n>>2)&7)<<2) ----
    const float* Wsrc = W1 + (size_t)t * E_N * E_N + n0;
    unsigned int* Bw = (unsigned int*)Bs;  // word idx = n*260 + swz(k2)
#pragma unroll
    for (int i = 0; i < 8; ++i) {
        int flat = i * 512 + tid;  // 0..4095
        int k2 = flat >> 4, nq = flat & 15;
        int k2s = k2 ^ ((nq & 7) << 2);  // (n>>2)&7 == nq for n = nq*4+j
        float4 va = *(const float4*)(Wsrc + (size_t)(2 * k2) * E_N + nq * 4);
        float4 vb = *(const float4*)(Wsrc + (size_t)(2 * k2 + 1) * E_N + nq * 4);
        Bw[(nq * 4 + 0) * 260 + k2s] = pk2(va.x, vb.x);
        Bw[(nq * 4 + 1) * 260 + k2s] = pk2(va.y, vb.y);
        Bw[(nq * 4 + 2) * 260 + k2s] = pk2(va.z, vb.z);
        Bw[(nq * 4 + 3) * 260 + k2s] = pk2(va.w, vb.w);
    }
    __syncthreads();  // rows_s + Bs final -- the ONLY barrier; main loop is barrier-free

    int MCn = (nt_c + 127) >> 7;       // total 128-row chunks for this tissue
    int MC = (MCn + 1 - h) >> 1;       // chunks of parity h owned by this block

    float* slab = yacc8 + (size_t)nt * B_N;

    for (int mc = 0; mc < MC; ++mc) {
        // lane (quad,l15): A-frag = 8 consecutive f32 k-values of row l15 (+w*16)
        int row = rows_s[mc * 128 + w * 16 + l15];
        const f32x4* pA4 = (const f32x4*)(g_exp + (size_t)row * E_N) + quad * 2;

        f32x4 acc[4];
#pragma unroll
        for (int ni = 0; ni < 4; ++ni) acc[ni] = (f32x4){0.f, 0.f, 0.f, 0.f};

        // depth-2 rolling prefetch; unroll 1 bounds liveness (anti-spill)
        f32x4 lo0 = pA4[0], hi0 = pA4[1];
        f32x4 lo1 = pA4[8], hi1 = pA4[9];
#pragma unroll 1
        for (int ks = 0; ks < 16; ++ks) {
            unsigned int uu[4] = {pk2(lo0[0], lo0[1]), pk2(lo0[2], lo0[3]),
                                  pk2(hi0[0], hi0[1]), pk2(hi0[2], hi0[3])};
            bf16x8 af;
            __builtin_memcpy(&af, uu, 16);
            lo0 = lo1; hi0 = hi1;
            if (ks < 14) { lo1 = pA4[(ks + 2) * 8]; hi1 = pA4[(ks + 2) * 8 + 1]; }
#pragma unroll
            for (int ni = 0; ni < 4; ++ni) {
                int bswz = ((ni * 4 + (l15 >> 2)) & 7) << 3;  // read-side XOR (shorts)
                bf16x8 bfr = *(const bf16x8*)(Bs + (ni * 16 + l15) * BP +
                                              ((ks * 32 + quad * 8) ^ bswz));
                acc[ni] = __builtin_amdgcn_mfma_f32_16x16x32_bf16(af, bfr, acc[ni], 0, 0, 0);
            }
        }

        // epilogue: gelu(acc + b1) * W2, dot over this block's 64 cols
        float pr[4] = {0.f, 0.f, 0.f, 0.f};
#pragma unroll
        for (int ni = 0; ni < 4; ++ni) {
#pragma unroll
            for (int r = 0; r < 4; ++r) {
                float u = acc[ni][r] + b1v[ni];
                float gg = 0.5f * u * (1.f + erff(u * 0.70710678118654752f));
                pr[r] = fmaf(gg, w2v[ni], pr[r]);
            }
        }
#pragma unroll
        for (int off = 1; off <= 8; off <<= 1)
#pragma unroll
            for (int r = 0; r < 4; ++r) pr[r] += __shfl_xor(pr[r], off, 64);

        if (l15 == 0) {
#pragma unroll
            for (int r = 0; r < 4; ++r) {
                int lidx = mc * 128 + w * 16 + quad * 4 + r;           // local rows_s index
                int grr = (2 * mc + h) * 128 + w * 16 + quad * 4 + r;  // global rank
                if (grr < nt_c) slab[rows_s[lidx]] = pr[r];
            }
        }
    }
}

__global__ void k_final8(const float* __restrict__ yacc8, const int* __restrict__ tv,
                         const float* __restrict__ b2, float* __restrict__ out) {
    int b = blockIdx.x * blockDim.x + threadIdx.x;
    if (b < B_N) {
        float x = b2[tv[b]];
#pragma unroll
        for (int s = 0; s < 8; ++s) x += yacc8[(size_t)s * B_N + b];
        out[b] = fmaxf(x, 0.f) + log1pf(expf(-fabsf(x)));  // stable softplus
    }
}

// ================= fallback (fp32 path, proven) =================
__global__ __launch_bounds__(256) void k_prep_sb(
    const int* __restrict__ tv, int* __restrict__ offs_g,
    int* __restrict__ rank, int* __restrict__ order, float* __restrict__ yacc) {
    __shared__ int lh[4][32], wcur[4][32], offs_s[33];
    int tid = threadIdx.x, w = tid >> 6;
    if (tid < 128) lh[tid >> 5][tid & 31] = 0;
    __syncthreads();
    int tval[32];
#pragma unroll
    for (int c = 0; c < 32; ++c) tval[c] = tv[c * 256 + tid];
#pragma unroll
    for (int c = 0; c < 32; ++c) atomicAdd(&lh[w][tval[c]], 1);
    __syncthreads();
    if (tid < 32) {
        int s = lh[0][tid] + lh[1][tid] + lh[2][tid] + lh[3][tid];
        int excl = 0;
#pragma unroll
        for (int i = 0; i < 32; ++i) {
            int v = __shfl(s, i, 64);
            if (i < tid) excl += v;
        }
        offs_s[tid] = excl;
        offs_g[tid] = excl;
        if (tid == 31) { offs_s[32] = excl + s; offs_g[32] = excl + s; }
    }
    __syncthreads();
    if (tid < 128) {
        int ww = tid >> 5, t = tid & 31;
        int s = offs_s[t];
        for (int w2 = 0; w2 < ww; ++w2) s += lh[w2][t];
        wcur[ww][t] = s;
    }
    __syncthreads();
#pragma unroll
    for (int c = 0; c < 32; ++c) {
        int b = c * 256 + tid;
        int pos = atomicAdd(&wcur[w][tval[c]], 1);
        rank[b] = pos;
        order[pos] = b;
    }
    float4 z = make_float4(0.f, 0.f, 0.f, 0.f);
#pragma unroll
    for (int c = 0; c < 8; ++c) *(float4*)(yacc + (c * 256 + tid) * 4) = z;
}

__global__ __launch_bounds__(256) void fb_gemm(
    const float* __restrict__ g_exp, const float* __restrict__ W1,
    const float* __restrict__ b1, const float* __restrict__ W2,
    const int* __restrict__ offs, const int* __restrict__ order,
    float* __restrict__ yacc) {
    int t = blockIdx.z;
    int base = offs[t];
    int n_t = offs[t + 1] - base;
    int m0 = blockIdx.y * 64;
    if (m0 >= n_t) return;
    int n0 = blockIdx.x * 128;

    __shared__ float As2[32][68];
    __shared__ float Bs2[32][128];
    __shared__ int sidx[64];

    int tid = threadIdx.x;
    if (tid < 64) {
        int m = m0 + tid;
        sidx[tid] = (m < n_t) ? order[base + m] : -1;
    }
    __syncthreads();

    int ty = tid >> 4, tx = tid & 15;
    float acc[4][8];
#pragma unroll
    for (int r = 0; r < 4; ++r)
#pragma unroll
        for (int c = 0; c < 8; ++c) acc[r][c] = 0.f;

    for (int k0 = 0; k0 < E_N; k0 += 32) {
#pragma unroll
        for (int p = 0; p < 2; ++p) {
            int idx = tid + 256 * p;
            int row = idx >> 3, kcq = idx & 7;
            int s = sidx[row];
            float4 v = make_float4(0.f, 0.f, 0.f, 0.f);
            if (s >= 0) v = *(const float4*)(g_exp + (size_t)s * E_N + k0 + kcq * 4);
            As2[kcq * 4 + 0][row] = v.x;
            As2[kcq * 4 + 1][row] = v.y;
            As2[kcq * 4 + 2][row] = v.z;
            As2[kcq * 4 + 3][row] = v.w;
        }
#pragma unroll
        for (int p = 0; p < 4; ++p) {
            int idx = tid + 256 * p;
            int kr = idx >> 5, c4 = idx & 31;
            *(float4*)(&Bs2[kr][c4 * 4]) =
                *(const float4*)(W1 + ((size_t)t * E_N + (k0 + kr)) * E_N + n0 + c4 * 4);
        }
        __syncthreads();
#pragma unroll
        for (int e = 0; e < 32; ++e) {
            float4 a = *(const float4*)(&As2[e][ty * 4]);
            float4 bA = *(const float4*)(&Bs2[e][tx * 4]);
            float4 bB = *(const float4*)(&Bs2[e][tx * 4 + 64]);
            float av[4] = {a.x, a.y, a.z, a.w};
            float bv[8] = {bA.x, bA.y, bA.z, bA.w, bB.x, bB.y, bB.z, bB.w};
#pragma unroll
            for (int r = 0; r < 4; ++r)
#pragma unroll
                for (int c = 0; c < 8; ++c) acc[r][c] = fmaf(av[r], bv[c], acc[r][c]);
        }
        __syncthreads();
    }

    float pr[4] = {0.f, 0.f, 0.f, 0.f};
#pragma unroll
    for (int c = 0; c < 8; ++c) {
        int n = n0 + tx * 4 + ((c >= 4) ? 64 : 0) + (c & 3);
        float bb = b1[t * E_N + n];
        float w2 = W2[t * E_N + n];
#pragma unroll
        for (int r = 0; r < 4; ++r) {
            float u = acc[r][c] + bb;
            float g = 0.5f * u * (1.f + erff(u * 0.70710678118654752f));
            pr[r] = fmaf(g, w2, pr[r]);
        }
    }
#pragma unroll
    for (int off = 8; off >= 1; off >>= 1)
#pragma unroll
        for (int r = 0; r < 4; ++r) pr[r] += __shfl_xor(pr[r], off, 64);

    if (tx == 0) {
#pragma unroll
        for (int r = 0; r < 4; ++r) {
            int m = m0 + ty * 4 + r;
            if (m < n_t) atomicAdd(&yacc[sidx[ty * 4 + r]], pr[r]);
        }
    }
}

__global__ void fb_final(const float* __restrict__ yacc, const int* __restrict__ tv,
                         const float* __restrict__ b2, float* __restrict__ out) {
    int b = blockIdx.x * blockDim.x + threadIdx.x;
    if (b < B_N) {
        float x = yacc[b] + b2[tv[b]];
        out[b] = fmaxf(x, 0.f) + log1pf(expf(-fabsf(x)));
    }
}

extern "C" void kernel_launch(void* const* d_in, const int* in_sizes, int n_in,
                              void* d_out, int out_size, void* d_ws, size_t ws_size,
                              hipStream_t stream) {
    const float* g_exp = (const float*)d_in[0];
    const int*   tv    = (const int*)d_in[1];
    const float* W1    = (const float*)d_in[2];
    const float* b1    = (const float*)d_in[3];
    const float* W2    = (const float*)d_in[4];
    const float* b2    = (const float*)d_in[5];
    float* out = (float*)d_out;

    char* ws = (char*)d_ws;

    if (ws_size >= (size_t)WS_REQ) {
        float* yacc8 = (float*)(ws + WS_YACC8);
        k_gemm_mfma<<<512, 512, 0, stream>>>(g_exp, W1, tv, b1, W2, yacc8);
        k_final8<<<32, 256, 0, stream>>>(yacc8, tv, b2, out);
    } else {
        int* offs   = (int*)(ws + WS_OFFS);
        int* rank   = (int*)(ws + WS_RANK);
        int* order  = (int*)(ws + WS_ORDER);
        float* yacc = (float*)(ws + WS_YACC);
        k_prep_sb<<<1, 256, 0, stream>>>(tv, offs, rank, order, yacc);
        fb_gemm<<<dim3(4, 8, 32), 256, 0, stream>>>(g_exp, W1, b1, W2, offs, order, yacc);
        fb_final<<<32, 256, 0, stream>>>(yacc, tv, b2, out);
    }
}

// Round 4
// 113.126 us; speedup vs baseline: 1.0129x; 1.0129x over previous
//
#include <hip/hip_runtime.h>
#include <hip/hip_bf16.h>
#include <math.h>

#define B_N 8192
#define E_N 512
#define T_N 32
#define BP 520  // B LDS pitch in shorts (1040 B, 16B-aligned rows)

typedef short bf16x8 __attribute__((ext_vector_type(8)));
typedef float f32x4 __attribute__((ext_vector_type(4)));

// ---------------- ws layout (bytes) ----------------
#define WS_OFFS   256      // fallback
#define WS_RANK   512      // fallback
#define WS_ORDER  33280    // fallback
#define WS_YACC   66048    // fallback
#define WS_YACC8  98816    // main: 8 x 8192 floats (256 KB), slab = nt
#define WS_REQ    (WS_YACC8 + 8 * B_N * 4)

static __device__ __forceinline__ unsigned short f2bf(float f) {
    unsigned int u = __float_as_uint(f);
    unsigned int r = u + 0x7fffu + ((u >> 16) & 1u);  // RNE
    return (unsigned short)(r >> 16);
}

// packed f32x2 -> bf16x2 (RNE)
static __device__ __forceinline__ unsigned int pk2(float a, float b) {
    __hip_bfloat162 h = __float22bfloat162_rn(float2{a, b});
    unsigned int u;
    __builtin_memcpy(&u, &h, 4);
    return u;
}

// ---------- fused GEMM v11: (tissue, 64-col slice, row-half) blocks.
// v10 post-mortem: kernel was latency-serialized, NOT BW/LDS-bound
// (673 GB/s HBM, MfmaUtil 4.6%). Two serial chains fixed here:
//  (a) main loop "rolling prefetch" had a register copy lo0=lo1 that
//      forced depth-1 (wait each iter on the load issued 1 iter ago).
//      Now: depth-4 ring of NAMED buffers, outer #pragma unroll 1,
//      4 explicit stages -> load issued 4 stages before use, liveness
//      hard-bounded at 8 in-flight loads (32 VGPRs).
//  (b) B-prologue load->pack->ds_write per-iter dependency kept ~2
//      loads in flight. Now two-phase (batch 8 loads, then pack/write).
// A read f32 directly (no cvtA kernel: -25 MB traffic, -1 dispatch).
// No main-loop barriers; 2 blocks/CU. wi%8 == t%8 keeps a tissue's 16
// blocks on one XCD (L2 reuse of A rows + shared W1 slice).
__global__ __launch_bounds__(512, 4) void k_gemm_mfma(
    const float* __restrict__ g_exp, const float* __restrict__ W1,
    const int* __restrict__ tv, const float* __restrict__ b1,
    const float* __restrict__ W2, float* __restrict__ yacc8) {
    int wi = blockIdx.x;
    int t = wi & 31, nt = (wi >> 5) & 7, h = wi >> 8;
    int n0 = nt * 64;

    int tid = threadIdx.x;
    int w = tid >> 6, lane = tid & 63;
    int quad = (lane >> 4) & 3, l15 = lane & 15;

    __shared__ __align__(16) unsigned short Bs[64 * BP];  // 66560 B, resident all kernel
    __shared__ int rows_s[256];  // this block's interleaved 128-row chunks
    __shared__ int wsum[8];

    // per-lane epilogue constants (cols n0 + ni*16 + l15)
    float b1v[4], w2v[4];
#pragma unroll
    for (int ni = 0; ni < 4; ++ni) {
        int n = t * E_N + n0 + ni * 16 + l15;
        b1v[ni] = b1[n];
        w2v[ni] = W2[n];
    }

    // ---- counting-sort slice for tissue t (512 thr x 16 items) ----
    int tvals[16];
    const int4* tvp = (const int4*)(tv + tid * 16);
#pragma unroll
    for (int j = 0; j < 4; ++j) ((int4*)tvals)[j] = tvp[j];
    int myc = 0;
#pragma unroll
    for (int j = 0; j < 16; ++j) myc += (tvals[j] == t) ? 1 : 0;
    int inc = myc;
#pragma unroll
    for (int o = 1; o < 64; o <<= 1) {
        int u = __shfl_up(inc, o, 64);
        if (lane >= o) inc += u;
    }
    if (lane == 63) wsum[w] = inc;
    if (tid < 256) rows_s[tid] = 0;
    __syncthreads();
    int n_t = 0, wbase = 0;
#pragma unroll
    for (int i = 0; i < 8; ++i) {
        int v = wsum[i];
        n_t += v;
        if (i < w) wbase += v;
    }
    int nt_c = n_t > 512 ? 512 : n_t;
    int rk = wbase + inc - myc;
    // scatter: half h owns 128-row chunks with (chunk & 1) == h
#pragma unroll
    for (int j = 0; j < 16; ++j)
        if (tvals[j] == t) {
            int rr = rk++;
            if (rr < 512 && (((rr >> 7) & 1) == h))
                rows_s[((rr >> 8) << 7) | (rr & 127)] = tid * 16 + j;
        }

    // ---- B prologue: W1[t][k][n0:n0+64] fp32 -> Bs[n][k] bf16 (k-major,
    // packed pairs, word idx XOR-swizzled). Two-phase x2: batch 4 iters'
    // loads (8 in flight), then pack+write -- overlaps cold-HBM latency.
    const float* Wsrc = W1 + (size_t)t * E_N * E_N + n0;
    unsigned int* Bw = (unsigned int*)Bs;  // word idx = n*260 + swz(k2)
#pragma unroll 1
    for (int g = 0; g < 2; ++g) {
        float4 va[4], vb[4];
#pragma unroll
        for (int i = 0; i < 4; ++i) {
            int flat = (g * 4 + i) * 512 + tid;  // 0..4095
            int k2 = flat >> 4, nq = flat & 15;
            va[i] = *(const float4*)(Wsrc + (size_t)(2 * k2) * E_N + nq * 4);
            vb[i] = *(const float4*)(Wsrc + (size_t)(2 * k2 + 1) * E_N + nq * 4);
        }
#pragma unroll
        for (int i = 0; i < 4; ++i) {
            int flat = (g * 4 + i) * 512 + tid;
            int k2 = flat >> 4, nq = flat & 15;
            int k2s = k2 ^ ((nq & 7) << 2);  // (n>>2)&7 == nq for n = nq*4+j
            Bw[(nq * 4 + 0) * 260 + k2s] = pk2(va[i].x, vb[i].x);
            Bw[(nq * 4 + 1) * 260 + k2s] = pk2(va[i].y, vb[i].y);
            Bw[(nq * 4 + 2) * 260 + k2s] = pk2(va[i].z, vb[i].z);
            Bw[(nq * 4 + 3) * 260 + k2s] = pk2(va[i].w, vb[i].w);
        }
    }
    __syncthreads();  // rows_s + Bs final -- the ONLY barrier; main loop is barrier-free

    int MCn = (nt_c + 127) >> 7;       // total 128-row chunks for this tissue
    int MC = (MCn + 1 - h) >> 1;       // chunks of parity h owned by this block

    float* slab = yacc8 + (size_t)nt * B_N;

    for (int mc = 0; mc < MC; ++mc) {
        // lane (quad,l15): A-frag = 8 consecutive f32 k-values of row l15 (+w*16)
        int row = rows_s[mc * 128 + w * 16 + l15];
        const f32x4* pA4 = (const f32x4*)(g_exp + (size_t)row * E_N) + quad * 2;

        f32x4 acc[4];
#pragma unroll
        for (int ni = 0; ni < 4; ++ni) acc[ni] = (f32x4){0.f, 0.f, 0.f, 0.f};

        // depth-4 ring: named buffers, no register copies (WAR bounds
        // in-flight loads at 8; load issued 4 stages before its use)
        f32x4 Alo0 = pA4[0],  Ahi0 = pA4[1];
        f32x4 Alo1 = pA4[8],  Ahi1 = pA4[9];
        f32x4 Alo2 = pA4[16], Ahi2 = pA4[17];
        f32x4 Alo3 = pA4[24], Ahi3 = pA4[25];

#define KSTEP(S, ks) do {                                                                   \
        unsigned int uu[4] = {pk2(Alo##S[0], Alo##S[1]), pk2(Alo##S[2], Alo##S[3]),         \
                              pk2(Ahi##S[0], Ahi##S[1]), pk2(Ahi##S[2], Ahi##S[3])};        \
        bf16x8 af;                                                                          \
        __builtin_memcpy(&af, uu, 16);                                                      \
        if (k4 < 3) {                                                                       \
            Alo##S = pA4[((ks) + 4) * 8];                                                   \
            Ahi##S = pA4[((ks) + 4) * 8 + 1];                                               \
        }                                                                                   \
        _Pragma("unroll") for (int ni = 0; ni < 4; ++ni) {                                  \
            int bswz = ((ni * 4 + (l15 >> 2)) & 7) << 3;  /* read-side XOR (shorts) */      \
            bf16x8 bfr = *(const bf16x8*)(Bs + (ni * 16 + l15) * BP +                       \
                                          (((ks) * 32 + quad * 8) ^ bswz));                 \
            acc[ni] = __builtin_amdgcn_mfma_f32_16x16x32_bf16(af, bfr, acc[ni], 0, 0, 0);   \
        }                                                                                   \
    } while (0)

#pragma unroll 1
        for (int k4 = 0; k4 < 4; ++k4) {
            int ksb = k4 * 4;
            KSTEP(0, ksb + 0);
            KSTEP(1, ksb + 1);
            KSTEP(2, ksb + 2);
            KSTEP(3, ksb + 3);
        }
#undef KSTEP

        // epilogue: gelu(acc + b1) * W2, dot over this block's 64 cols
        float pr[4] = {0.f, 0.f, 0.f, 0.f};
#pragma unroll
        for (int ni = 0; ni < 4; ++ni) {
#pragma unroll
            for (int r = 0; r < 4; ++r) {
                float u = acc[ni][r] + b1v[ni];
                float gg = 0.5f * u * (1.f + erff(u * 0.70710678118654752f));
                pr[r] = fmaf(gg, w2v[ni], pr[r]);
            }
        }
#pragma unroll
        for (int off = 1; off <= 8; off <<= 1)
#pragma unroll
            for (int r = 0; r < 4; ++r) pr[r] += __shfl_xor(pr[r], off, 64);

        if (l15 == 0) {
#pragma unroll
            for (int r = 0; r < 4; ++r) {
                int lidx = mc * 128 + w * 16 + quad * 4 + r;           // local rows_s index
                int grr = (2 * mc + h) * 128 + w * 16 + quad * 4 + r;  // global rank
                if (grr < nt_c) slab[rows_s[lidx]] = pr[r];
            }
        }
    }
}

__global__ void k_final8(const float* __restrict__ yacc8, const int* __restrict__ tv,
                         const float* __restrict__ b2, float* __restrict__ out) {
    int b = blockIdx.x * blockDim.x + threadIdx.x;
    if (b < B_N) {
        float x = b2[tv[b]];
#pragma unroll
        for (int s = 0; s < 8; ++s) x += yacc8[(size_t)s * B_N + b];
        out[b] = fmaxf(x, 0.f) + log1pf(expf(-fabsf(x)));  // stable softplus
    }
}

// ================= fallback (fp32 path, proven) =================
__global__ __launch_bounds__(256) void k_prep_sb(
    const int* __restrict__ tv, int* __restrict__ offs_g,
    int* __restrict__ rank, int* __restrict__ order, float* __restrict__ yacc) {
    __shared__ int lh[4][32], wcur[4][32], offs_s[33];
    int tid = threadIdx.x, w = tid >> 6;
    if (tid < 128) lh[tid >> 5][tid & 31] = 0;
    __syncthreads();
    int tval[32];
#pragma unroll
    for (int c = 0; c < 32; ++c) tval[c] = tv[c * 256 + tid];
#pragma unroll
    for (int c = 0; c < 32; ++c) atomicAdd(&lh[w][tval[c]], 1);
    __syncthreads();
    if (tid < 32) {
        int s = lh[0][tid] + lh[1][tid] + lh[2][tid] + lh[3][tid];
        int excl = 0;
#pragma unroll
        for (int i = 0; i < 32; ++i) {
            int v = __shfl(s, i, 64);
            if (i < tid) excl += v;
        }
        offs_s[tid] = excl;
        offs_g[tid] = excl;
        if (tid == 31) { offs_s[32] = excl + s; offs_g[32] = excl + s; }
    }
    __syncthreads();
    if (tid < 128) {
        int ww = tid >> 5, t = tid & 31;
        int s = offs_s[t];
        for (int w2 = 0; w2 < ww; ++w2) s += lh[w2][t];
        wcur[ww][t] = s;
    }
    __syncthreads();
#pragma unroll
    for (int c = 0; c < 32; ++c) {
        int b = c * 256 + tid;
        int pos = atomicAdd(&wcur[w][tval[c]], 1);
        rank[b] = pos;
        order[pos] = b;
    }
    float4 z = make_float4(0.f, 0.f, 0.f, 0.f);
#pragma unroll
    for (int c = 0; c < 8; ++c) *(float4*)(yacc + (c * 256 + tid) * 4) = z;
}

__global__ __launch_bounds__(256) void fb_gemm(
    const float* __restrict__ g_exp, const float* __restrict__ W1,
    const float* __restrict__ b1, const float* __restrict__ W2,
    const int* __restrict__ offs, const int* __restrict__ order,
    float* __restrict__ yacc) {
    int t = blockIdx.z;
    int base = offs[t];
    int n_t = offs[t + 1] - base;
    int m0 = blockIdx.y * 64;
    if (m0 >= n_t) return;
    int n0 = blockIdx.x * 128;

    __shared__ float As2[32][68];
    __shared__ float Bs2[32][128];
    __shared__ int sidx[64];

    int tid = threadIdx.x;
    if (tid < 64) {
        int m = m0 + tid;
        sidx[tid] = (m < n_t) ? order[base + m] : -1;
    }
    __syncthreads();

    int ty = tid >> 4, tx = tid & 15;
    float acc[4][8];
#pragma unroll
    for (int r = 0; r < 4; ++r)
#pragma unroll
        for (int c = 0; c < 8; ++c) acc[r][c] = 0.f;

    for (int k0 = 0; k0 < E_N; k0 += 32) {
#pragma unroll
        for (int p = 0; p < 2; ++p) {
            int idx = tid + 256 * p;
            int row = idx >> 3, kcq = idx & 7;
            int s = sidx[row];
            float4 v = make_float4(0.f, 0.f, 0.f, 0.f);
            if (s >= 0) v = *(const float4*)(g_exp + (size_t)s * E_N + k0 + kcq * 4);
            As2[kcq * 4 + 0][row] = v.x;
            As2[kcq * 4 + 1][row] = v.y;
            As2[kcq * 4 + 2][row] = v.z;
            As2[kcq * 4 + 3][row] = v.w;
        }
#pragma unroll
        for (int p = 0; p < 4; ++p) {
            int idx = tid + 256 * p;
            int kr = idx >> 5, c4 = idx & 31;
            *(float4*)(&Bs2[kr][c4 * 4]) =
                *(const float4*)(W1 + ((size_t)t * E_N + (k0 + kr)) * E_N + n0 + c4 * 4);
        }
        __syncthreads();
#pragma unroll
        for (int e = 0; e < 32; ++e) {
            float4 a = *(const float4*)(&As2[e][ty * 4]);
            float4 bA = *(const float4*)(&Bs2[e][tx * 4]);
            float4 bB = *(const float4*)(&Bs2[e][tx * 4 + 64]);
            float av[4] = {a.x, a.y, a.z, a.w};
            float bv[8] = {bA.x, bA.y, bA.z, bA.w, bB.x, bB.y, bB.z, bB.w};
#pragma unroll
            for (int r = 0; r < 4; ++r)
#pragma unroll
                for (int c = 0; c < 8; ++c) acc[r][c] = fmaf(av[r], bv[c], acc[r][c]);
        }
        __syncthreads();
    }

    float pr[4] = {0.f, 0.f, 0.f, 0.f};
#pragma unroll
    for (int c = 0; c < 8; ++c) {
        int n = n0 + tx * 4 + ((c >= 4) ? 64 : 0) + (c & 3);
        float bb = b1[t * E_N + n];
        float w2 = W2[t * E_N + n];
#pragma unroll
        for (int r = 0; r < 4; ++r) {
            float u = acc[r][c] + bb;
            float g = 0.5f * u * (1.f + erff(u * 0.70710678118654752f));
            pr[r] = fmaf(g, w2, pr[r]);
        }
    }
#pragma unroll
    for (int off = 8; off >= 1; off >>= 1)
#pragma unroll
        for (int r = 0; r < 4; ++r) pr[r] += __shfl_xor(pr[r], off, 64);

    if (tx == 0) {
#pragma unroll
        for (int r = 0; r < 4; ++r) {
            int m = m0 + ty * 4 + r;
            if (m < n_t) atomicAdd(&yacc[sidx[ty * 4 + r]], pr[r]);
        }
    }
}

__global__ void fb_final(const float* __restrict__ yacc, const int* __restrict__ tv,
                         const float* __restrict__ b2, float* __restrict__ out) {
    int b = blockIdx.x * blockDim.x + threadIdx.x;
    if (b < B_N) {
        float x = yacc[b] + b2[tv[b]];
        out[b] = fmaxf(x, 0.f) + log1pf(expf(-fabsf(x)));
    }
}

extern "C" void kernel_launch(void* const* d_in, const int* in_sizes, int n_in,
                              void* d_out, int out_size, void* d_ws, size_t ws_size,
                              hipStream_t stream) {
    const float* g_exp = (const float*)d_in[0];
    const int*   tv    = (const int*)d_in[1];
    const float* W1    = (const float*)d_in[2];
    const float* b1    = (const float*)d_in[3];
    const float* W2    = (const float*)d_in[4];
    const float* b2    = (const float*)d_in[5];
    float* out = (float*)d_out;

    char* ws = (char*)d_ws;

    if (ws_size >= (size_t)WS_REQ) {
        float* yacc8 = (float*)(ws + WS_YACC8);
        k_gemm_mfma<<<512, 512, 0, stream>>>(g_exp, W1, tv, b1, W2, yacc8);
        k_final8<<<32, 256, 0, stream>>>(yacc8, tv, b2, out);
    } else {
        int* offs   = (int*)(ws + WS_OFFS);
        int* rank   = (int*)(ws + WS_RANK);
        int* order  = (int*)(ws + WS_ORDER);
        float* yacc = (float*)(ws + WS_YACC);
        k_prep_sb<<<1, 256, 0, stream>>>(tv, offs, rank, order, yacc);
        fb_gemm<<<dim3(4, 8, 32), 256, 0, stream>>>(g_exp, W1, b1, W2, offs, order, yacc);
        fb_final<<<32, 256, 0, stream>>>(yacc, tv, b2, out);
    }
}